// Round 5
// baseline (281.197 us; speedup 1.0000x reference)
//
#include <hip/hip_runtime.h>
#include <hip/hip_bf16.h>

#define NN 10000
#define KK 32
#define DDIRIN 10
#define DDIR 64
#define DD 128          // D_DIST == D_DIST_IN == D_ATOM == 128

typedef short bf16x8 __attribute__((ext_vector_type(8)));
typedef float f32x4  __attribute__((ext_vector_type(4)));

__device__ __forceinline__ float silu_f(float x) { return x / (1.0f + __expf(-x)); }

// packed f32x2 -> bf16x2 (RNE) -> raw shorts
__device__ __forceinline__ ushort2 pk_bf16(float a, float b) {
    __hip_bfloat162 h = __float22bfloat162_rn(float2{a, b});
    union { __hip_bfloat162 h; ushort2 u; } v; v.h = h;
    return v.u;
}

// One fused kernel: block = 4 nodes (128 edge rows), 256 threads, ONE barrier.
//   dims 0..128  : MFMA GEMM  silu(E @ dW + db), masked-mean via zero-row trick
//   dims 128..512: per-wave gather segments (ballot-compacted neighbor list),
//                  sender-dir MLP recomputed in-register (no workspace).
__global__ __launch_bounds__(256, 2) void gnn_fused_kernel(
    const int*   __restrict__ an,      // [N]
    const float* __restrict__ nde,     // [N,10]
    const float* __restrict__ edist,   // [N,32,128]
    const int*   __restrict__ nl,      // [N,32]
    const int*   __restrict__ nmask,   // [N,32]
    const float* __restrict__ semb,    // [100,128]
    const float* __restrict__ temb,    // [100,128]
    const float* __restrict__ sW, const float* __restrict__ sb,   // [10,64],[64]
    const float* __restrict__ tW, const float* __restrict__ tb,   // [10,64],[64]
    const float* __restrict__ dW, const float* __restrict__ db,   // [128,128],[128]
    float* __restrict__ out)           // [N,512]
{
    const int tid  = threadIdx.x;
    const int wid  = tid >> 6;       // wave -> GEMM cols [32*wid, 32*wid+32); seg node n0+wid
    const int lane = tid & 63;
    const int l15  = lane & 15;
    const int quad = lane >> 4;
    const int n0   = blockIdx.x * 4;

    __shared__ __align__(16) short s_E[128 * 128];   // 32 KB bf16, swizzled
    __shared__ int   s_idx[4][KK];
    __shared__ int   s_aidx[4][KK];
    __shared__ float s_cnt[4];

    // ---- per-wave: neighbor compaction for node n0+wid (pre-barrier) ----
    int cnt;
    {
        int j = 0; bool act = false;
        if (lane < KK) {
            j   = nl[(n0 + wid) * KK + lane];
            act = (nmask[(n0 + wid) * KK + lane] != 0);
        }
        unsigned long long bits = __ballot(act);
        cnt = (int)__popcll(bits);
        if (act) {
            int rank = (int)__popcll(bits & ((1ull << lane) - 1ull));
            s_idx[wid][rank]  = j;
            s_aidx[wid][rank] = an[j];
        }
        if (lane == 0) s_cnt[wid] = (float)cnt;
    }

    // ---- B fragments: dW cvt'd to bf16, in registers ----
    // lane holds k = t*32 + quad*8 + j, col = ncol
    bf16x8 bfrag[2][4];
    float  bias[2];
#pragma unroll
    for (int c2 = 0; c2 < 2; ++c2) {
        int ncol = (2 * wid + c2) * 16 + l15;
        bias[c2] = db[ncol];
#pragma unroll
        for (int t = 0; t < 4; ++t) {
            bf16x8 v;
#pragma unroll
            for (int j2 = 0; j2 < 4; ++j2) {
                int k0 = t * 32 + quad * 8 + 2 * j2;
                ushort2 u = pk_bf16(dW[k0 * DD + ncol], dW[(k0 + 1) * DD + ncol]);
                v[2 * j2]     = (short)u.x;
                v[2 * j2 + 1] = (short)u.y;
            }
            bfrag[c2][t] = v;
        }
    }

    // ---- stage 4 edist rows (64 KB f32) -> bf16 LDS, zeroing masked rows ----
    // Thread t, iter i: 8 consecutive f32 -> one ds_write_b128 (swizzled kb).
    {
        const float4* E4 = reinterpret_cast<const float4*>(edist + (size_t)n0 * (KK * DD));
        const int* nm = nmask + n0 * KK;
#pragma unroll
        for (int i = 0; i < 8; ++i) {
            int f0  = 2 * tid + 512 * i;
            int row = f0 >> 5;
            float4 a = E4[f0], b = E4[f0 + 1];
            ushort2 u0 = pk_bf16(a.x, a.y), u1 = pk_bf16(a.z, a.w);
            ushort2 u2 = pk_bf16(b.x, b.y), u3 = pk_bf16(b.z, b.w);
            bf16x8 v;
            v[0] = (short)u0.x; v[1] = (short)u0.y; v[2] = (short)u1.x; v[3] = (short)u1.y;
            v[4] = (short)u2.x; v[5] = (short)u2.y; v[6] = (short)u3.x; v[7] = (short)u3.y;
            bf16x8 z;
#pragma unroll
            for (int q = 0; q < 8; ++q) z[q] = 0;
            v = (nm[row] != 0) ? v : z;
            int kb = tid & 15;
            int sw = kb ^ (row & 7);
            *reinterpret_cast<bf16x8*>(&s_E[row * 128 + sw * 8]) = v;
        }
    }
    __syncthreads();   // the ONLY barrier

    // ---- MFMA: C[128 rows x 128 cols]; wave owns 32 cols, all 8 row-tiles ----
    f32x4 acc[8][2];
#pragma unroll
    for (int rt = 0; rt < 8; ++rt)
#pragma unroll
        for (int c2 = 0; c2 < 2; ++c2)
#pragma unroll
            for (int g = 0; g < 4; ++g) acc[rt][c2][g] = 0.0f;

#pragma unroll
    for (int rt = 0; rt < 8; ++rt) {
        bf16x8 af[4];
        int r = rt * 16 + l15;
#pragma unroll
        for (int t = 0; t < 4; ++t) {
            int kb = (4 * t + quad) ^ (l15 & 7);
            af[t] = *reinterpret_cast<const bf16x8*>(&s_E[r * 128 + kb * 8]);
        }
#pragma unroll
        for (int t = 0; t < 4; ++t) {
            acc[rt][0] = __builtin_amdgcn_mfma_f32_16x16x32_bf16(af[t], bfrag[0][t], acc[rt][0], 0, 0, 0);
            acc[rt][1] = __builtin_amdgcn_mfma_f32_16x16x32_bf16(af[t], bfrag[1][t], acc[rt][1], 0, 0, 0);
        }
    }

    // ---- GEMM epilogue. D layout: col=l15, row=quad*4+g (+16*rt). Node nd = rt {2nd,2nd+1}.
    // Zeroed rows contribute exactly silu(bias): sum_masked = sum_all - (32-cnt)*silu(bias).
#pragma unroll
    for (int c2 = 0; c2 < 2; ++c2) {
        float sbv = silu_f(bias[c2]);
#pragma unroll
        for (int nd = 0; nd < 4; ++nd) {
            float p = 0.0f;
#pragma unroll
            for (int h = 0; h < 2; ++h) {
                int rt = 2 * nd + h;
#pragma unroll
                for (int g = 0; g < 4; ++g)
                    p += silu_f(acc[rt][c2][g] + bias[c2]);
            }
            p += __shfl_xor(p, 16);
            p += __shfl_xor(p, 32);
            if (quad == nd) {
                float c = s_cnt[nd];
                float val = (p - (32.0f - c) * sbv) / (c + 1e-5f);
                out[(size_t)(n0 + nd) * 512 + (2 * wid + c2) * 16 + l15] = val;
            }
        }
    }

    // ---- seg part: wave wid handles node n = n0+wid, dims 128..512 ----
    {
        const int n = n0 + wid;
        const float invv  = 1.0f / ((float)cnt + 1e-5f);
        const float scale = (float)cnt * invv;
        float* outn = out + (size_t)n * 512;

        // sender dir (128..192): recompute MLP per compacted neighbor, d = lane
        {
            float wreg[DDIRIN];
#pragma unroll
            for (int q = 0; q < DDIRIN; ++q) wreg[q] = sW[q * DDIR + lane];
            float bsv = sb[lane];
            float s = 0.0f;
            for (int i = 0; i < cnt; ++i) {
                const float* x = nde + s_idx[wid][i] * DDIRIN;
                float a = bsv;
#pragma unroll
                for (int q = 0; q < DDIRIN; ++q)
                    a = fmaf(x[q], wreg[q], a);
                s += silu_f(a);
            }
            outn[128 + lane] = s * invv;
        }

        // sender atom (192..320)
        {
            float s0 = 0.0f, s1 = 0.0f;
#pragma unroll 4
            for (int i = 0; i < cnt; ++i) {
                int a = s_aidx[wid][i];
                s0 += semb[a * DD + lane];
                s1 += semb[a * DD + 64 + lane];
            }
            outn[192 + lane] = s0 * invv;
            outn[256 + lane] = s1 * invv;
        }

        // recv dir (320..384): MLP for own node
        {
            float a = tb[lane];
            const float* x = nde + n * DDIRIN;
#pragma unroll
            for (int q = 0; q < DDIRIN; ++q)
                a = fmaf(x[q], tW[q * DDIR + lane], a);
            outn[320 + lane] = silu_f(a) * scale;
        }

        // recv atom (384..512)
        {
            int ann = an[n];
            outn[384 + lane] = temb[ann * DD + lane] * scale;
            outn[448 + lane] = temb[ann * DD + 64 + lane] * scale;
        }
    }
}

extern "C" void kernel_launch(void* const* d_in, const int* in_sizes, int n_in,
                              void* d_out, int out_size, void* d_ws, size_t ws_size,
                              hipStream_t stream) {
    const int*   an    = (const int*)  d_in[0];
    const float* nde   = (const float*)d_in[1];
    const float* edist = (const float*)d_in[2];
    const int*   nl    = (const int*)  d_in[3];
    const int*   nmask = (const int*)  d_in[4];
    const float* semb  = (const float*)d_in[5];
    const float* temb  = (const float*)d_in[6];
    const float* sW    = (const float*)d_in[7];
    const float* sb    = (const float*)d_in[8];
    const float* tW    = (const float*)d_in[9];
    const float* tb    = (const float*)d_in[10];
    const float* dW    = (const float*)d_in[11];
    const float* db    = (const float*)d_in[12];
    float* out = (float*)d_out;

    gnn_fused_kernel<<<NN / 4, 256, 0, stream>>>(
        an, nde, edist, nl, nmask, semb, temb, sW, sb, tW, tb, dW, db, out);
}